// Round 8
// baseline (254.213 us; speedup 1.0000x reference)
//
#include <hip/hip_runtime.h>
#include <math.h>

#define S_LEN 4096
#define F_DIM 512
#define PSPLIT 8
#define FIXED_M 4.0f
#define SCALE_QK 0.04415108f   // 1/sqrt(513)

typedef __attribute__((ext_vector_type(8))) short bf16x8;
typedef __attribute__((ext_vector_type(4))) float f32x4;

__device__ __forceinline__ unsigned short f2bf(float x) {
    union { float f; unsigned u; } v; v.f = x;
    unsigned r = v.u + 0x7fffu + ((v.u >> 16) & 1u);
    return (unsigned short)(r >> 16);
}
__device__ __forceinline__ float bf2f(unsigned short b) {
    union { unsigned u; float f; } v; v.u = ((unsigned)b) << 16;
    return v.f;
}
__device__ __forceinline__ void load_lds16(const void* g, void* l) {
    __builtin_amdgcn_global_load_lds(
        (const __attribute__((address_space(1))) unsigned int*)g,
        (__attribute__((address_space(3))) unsigned int*)l, 16, 0, 0);
}

// ---------------- fused fp32 -> bf16 casts ----------------
struct CastArgs {
    const float* src[7];
    unsigned short* dst[7];
    int n4[7];
};
__global__ void cast_all(CastArgs a) {
    int r = blockIdx.y;
    int i = blockIdx.x * blockDim.x + threadIdx.x;
    if (i >= a.n4[r]) return;
    float4 v = ((const float4*)a.src[r])[i];
    ushort4 o;
    o.x = f2bf(v.x); o.y = f2bf(v.y); o.z = f2bf(v.z); o.w = f2bf(v.w);
    ((ushort4*)a.dst[r])[i] = o;
}

// ---------------- bf16 transpose: src [S][F] -> dst [F][S] ----------------
__global__ void transpose_bf16(const unsigned short* __restrict__ src,
                               unsigned short* __restrict__ dst) {
    __shared__ __align__(16) unsigned short tile[64][72];
    const int s0 = blockIdx.x * 64, f0 = blockIdx.y * 64;
    const int tid = threadIdx.x;
#pragma unroll
    for (int it = 0; it < 2; ++it) {
        int u = it * 256 + tid;
        int r = u >> 3, c = (u & 7) * 8;
        *(uint4*)&tile[r][c] = *(const uint4*)(src + (size_t)(s0 + r) * F_DIM + f0 + c);
    }
    __syncthreads();
#pragma unroll
    for (int it = 0; it < 2; ++it) {
        int u = it * 256 + tid;
        int fl = u >> 3, sc = (u & 7) * 8;
        unsigned short tmp[8];
#pragma unroll
        for (int i = 0; i < 8; ++i) tmp[i] = tile[sc + i][fl];
        *(uint4*)(dst + (size_t)(f0 + fl) * S_LEN + s0 + sc) = *(uint4*)tmp;
    }
}

struct GemmDesc {
    const unsigned short* X;
    const unsigned short* W;
    const float* bias;
    unsigned short* out_bf;
    float* out_f32;
    int relu;
};
struct GemmArgs { GemmDesc d[5]; };

// =====================================================================
// Champion (R1/R3) 256x256 8-phase K-loop — byte-identical to the
// 199.4 µs version (A staged at phase 0, B at phase 1, vmcnt(0) at
// phase 3). Used by the projections only now.
// =====================================================================
#define FRAGA(qm) { _Pragma("unroll") for (int mt = 0; mt < 4; ++mt) { \
    const int ro = (aw + (qm) * 64 + mt * 16) * 64 + rbase; \
    af[mt][0] = *(const bf16x8*)&Ac[ro + q0]; \
    af[mt][1] = *(const bf16x8*)&Ac[ro + q1]; } }

#define FRAGB(qn) { _Pragma("unroll") for (int nt = 0; nt < 2; ++nt) { \
    const int ro = (bw + (qn) * 32 + nt * 16) * 64 + rbase; \
    bf[nt][0] = *(const bf16x8*)&Bc[ro + q0]; \
    bf[nt][1] = *(const bf16x8*)&Bc[ro + q1]; } }

#define MMQ(qm, qn) { __builtin_amdgcn_s_setprio(1); \
    _Pragma("unroll") for (int kh = 0; kh < 2; ++kh) \
    _Pragma("unroll") for (int mt = 0; mt < 4; ++mt) \
    _Pragma("unroll") for (int nt = 0; nt < 2; ++nt) \
      acc[(qm) * 4 + mt][(qn) * 2 + nt] = __builtin_amdgcn_mfma_f32_16x16x32_bf16( \
          af[mt][kh], bf[nt][kh], acc[(qm) * 4 + mt][(qn) * 2 + nt], 0, 0, 0); \
    __builtin_amdgcn_s_setprio(0); }

__device__ __forceinline__ void kloop256(const unsigned short* __restrict__ A, int lda,
                                         const unsigned short* __restrict__ B, int ldb,
                                         int m0, int n0, int kbase,
                                         unsigned short* smem, f32x4 acc[8][4]) {
    const int tid = threadIdx.x;
    const int w = tid >> 6, l = tid & 63;
    const int ln = l & 15, quad = l >> 4, lnx = l & 7;
    const int wm = w >> 2, wn = w & 3;
    const int srow = l >> 3;
    const int scol = (lnx ^ srow) * 8;
    const int rbase = ln * 64;
    const int q0 = (quad ^ lnx) * 8;
    const int q1 = ((4 + quad) ^ lnx) * 8;
    unsigned short* As = smem;
    unsigned short* Bs = smem + 32768;
    const unsigned short* Asrc = A + (size_t)(m0 + srow) * lda + kbase + scol;
    const unsigned short* Bsrc = B + (size_t)(n0 + srow) * ldb + kbase + scol;

    auto stageA = [&](int dd, int ktn) {
#pragma unroll
        for (int j = 0; j < 4; ++j) {
            int chunk = w * 4 + j;
            load_lds16(Asrc + (size_t)(chunk * 8) * lda + ktn * 64,
                       &As[dd * 16384 + chunk * 512]);
        }
    };
    auto stageB = [&](int dd, int ktn) {
#pragma unroll
        for (int j = 0; j < 4; ++j) {
            int chunk = w * 4 + j;
            load_lds16(Bsrc + (size_t)(chunk * 8) * ldb + ktn * 64,
                       &Bs[dd * 16384 + chunk * 512]);
        }
    };

    stageA(0, 0); stageB(0, 0);
    asm volatile("s_waitcnt vmcnt(0)" ::: "memory");
    __builtin_amdgcn_s_barrier();

#pragma unroll
    for (int kt = 0; kt < 8; ++kt) {
        const int d = kt & 1;
        const unsigned short* Ac = &As[d * 16384];
        const unsigned short* Bc = &Bs[d * 16384];
        const int aw = wm * 128, bw = wn * 64;
        bf16x8 af[4][2], bf[2][2];

        FRAGA(0); FRAGB(0);
        if (kt < 7) stageA(d ^ 1, kt + 1);
        __builtin_amdgcn_s_barrier();
        MMQ(0, 0);
        __builtin_amdgcn_s_barrier();

        FRAGB(1);
        if (kt < 7) stageB(d ^ 1, kt + 1);
        __builtin_amdgcn_s_barrier();
        MMQ(0, 1);
        __builtin_amdgcn_s_barrier();

        FRAGA(1);
        __builtin_amdgcn_s_barrier();
        MMQ(1, 1);
        __builtin_amdgcn_s_barrier();

        FRAGB(0);
        __builtin_amdgcn_s_barrier();
        MMQ(1, 0);
        asm volatile("s_waitcnt vmcnt(0)" ::: "memory");
        __builtin_amdgcn_s_barrier();
    }
}

// ---------------- projections: out = op(X @ W^T + b), 5 gemms ----------------
__launch_bounds__(512, 2)
__global__ void gemm_proj2(GemmArgs args) {
    extern __shared__ unsigned short smem[];
    const GemmDesc d = args.d[blockIdx.y >> 1];
    const int n0 = (blockIdx.y & 1) * 256;
    const int m0 = blockIdx.x * 256;
    f32x4 acc[8][4];
    f32x4 z = {0.f, 0.f, 0.f, 0.f};
#pragma unroll
    for (int i = 0; i < 8; ++i)
#pragma unroll
        for (int j = 0; j < 4; ++j) acc[i][j] = z;

    kloop256(d.X, F_DIM, d.W, F_DIM, m0, n0, 0, smem, acc);

    const int tid = threadIdx.x;
    const int w = tid >> 6, l = tid & 63, quad = l >> 4, ln = l & 15;
    const int wm = w >> 2, wn = w & 3;
#pragma unroll
    for (int mi = 0; mi < 8; ++mi)
#pragma unroll
        for (int ni = 0; ni < 4; ++ni)
#pragma unroll
            for (int r = 0; r < 4; ++r) {
                int row = m0 + wm * 128 + mi * 16 + quad * 4 + r;
                int col = n0 + wn * 64 + ni * 16 + ln;
                float vv = acc[mi][ni][r] + d.bias[col];
                if (d.relu) vv = fmaxf(vv, 0.f);
                if (d.out_bf)  d.out_bf[(size_t)row * F_DIM + col] = f2bf(vv);
                if (d.out_f32) d.out_f32[(size_t)row * F_DIM + col] = vv;
            }
}

// =====================================================================
// gemm_fa: fused exp+pv. Grid 256 = 32 Q-strips(128) x 8 KV-splits(512).
// Per KV-subtile (128 rows of kk):
//   1) S = qq[m0:+128] @ kk[kvb:+128]^T  (K=512, dbuf, drain-at-top)
//   2) P = exp(S*scale - M) -> 32KB LDS tile (XOR-swizzled); rowsum regs
//   3) O += P @ vt_slice^T  (A from LDS Ps — zero global A traffic;
//      vt streamed in 64KB halves through the reused As/Bs space)
// P never touches global memory (saves 67 MB round-trip vs exp2+pv2).
// Accumulation order identical to exp2+pv2 -> absmax must be unchanged.
// LDS: AsU 32KB dbuf(qq) | BsU 32KB dbuf(kk) [PV: As+Bs = 64KB vt buf]
//      | PsU 32KB. Total 128KB.
// Ps swizzle (16 col-blocks of 8 bf16): phys_cb = ((cb&7)^(row&7))|(cb&8)
// — involution, applied on write and read.
// =====================================================================
__launch_bounds__(512, 2)
__global__ void gemm_fa(const unsigned short* __restrict__ qq,  // [S][F]
                        const unsigned short* __restrict__ kk,  // [S][F]
                        const unsigned short* __restrict__ vt,  // [F][S]
                        unsigned short* __restrict__ O_p,       // [PSPLIT][S][F]
                        float* __restrict__ lpart) {            // [S][32]
    extern __shared__ unsigned short smem[];
    unsigned short* AsU = smem;            // 16384 ushorts: qq dbuf
    unsigned short* BsU = smem + 16384;    // 16384 ushorts: kk dbuf
    unsigned short* PsU = smem + 49152;    // 16384 ushorts: P [128][128]
    const int bid = blockIdx.x;
    const int m0 = (bid & 31) * 128;
    const int split = bid >> 5;            // 0..7

    const int tid = threadIdx.x;
    const int w = tid >> 6, l = tid & 63;
    const int ln = l & 15, quad = l >> 4, lnx = l & 7;
    const int wm = w >> 2, wn = w & 3;     // 2M x 4N waves
    const int srow = l >> 3;
    const int scol = (lnx ^ srow) * 8;
    const int q0 = (quad ^ lnx) * 8;
    const int q1 = ((4 + quad) ^ lnx) * 8;

    f32x4 o[4][8];
    float rs[4][4];
    f32x4 z = {0.f, 0.f, 0.f, 0.f};
#pragma unroll
    for (int i = 0; i < 4; ++i) {
#pragma unroll
        for (int jj = 0; jj < 8; ++jj) o[i][jj] = z;
#pragma unroll
        for (int jj = 0; jj < 4; ++jj) rs[i][jj] = 0.f;
    }

    const unsigned short* Aq = qq + (size_t)(m0 + srow) * F_DIM + scol;

    for (int j = 0; j < 4; ++j) {          // KV subtiles of 128
        const int kvb = split * 512 + j * 128;
        const unsigned short* Bk = kk + (size_t)(kvb + srow) * F_DIM + scol;

        // ---- 1) QK^T: K=512, 8 dbuf K-tiles, drain at top of each ----
        f32x4 sa[4][2];
#pragma unroll
        for (int i = 0; i < 4; ++i) { sa[i][0] = z; sa[i][1] = z; }

        auto stageQ = [&](int dd, int kt) {
#pragma unroll
            for (int jj = 0; jj < 2; ++jj) {
                int chunk = w * 2 + jj;    // 16 chunks of 8 rows each
                load_lds16(Aq + (size_t)(chunk * 8) * F_DIM + kt * 64,
                           &AsU[dd * 8192 + chunk * 512]);
                load_lds16(Bk + (size_t)(chunk * 8) * F_DIM + kt * 64,
                           &BsU[dd * 8192 + chunk * 512]);
            }
        };
        stageQ(0, 0);
#pragma unroll
        for (int kt = 0; kt < 8; ++kt) {
            const int d = kt & 1;
            asm volatile("s_waitcnt vmcnt(0)" ::: "memory");  // tile kt landed
            __builtin_amdgcn_s_barrier();
            bf16x8 af[4][2], bf[2][2];
#pragma unroll
            for (int mt = 0; mt < 4; ++mt) {
                int ro = d * 8192 + (wm * 64 + mt * 16 + ln) * 64;
                af[mt][0] = *(const bf16x8*)&AsU[ro + q0];
                af[mt][1] = *(const bf16x8*)&AsU[ro + q1];
            }
#pragma unroll
            for (int nt = 0; nt < 2; ++nt) {
                int ro = d * 8192 + (wn * 32 + nt * 16 + ln) * 64;
                bf[nt][0] = *(const bf16x8*)&BsU[ro + q0];
                bf[nt][1] = *(const bf16x8*)&BsU[ro + q1];
            }
            if (kt < 7) stageQ(d ^ 1, kt + 1);   // one-iteration cover
            __builtin_amdgcn_s_setprio(1);
#pragma unroll
            for (int kh = 0; kh < 2; ++kh)
#pragma unroll
                for (int mt = 0; mt < 4; ++mt)
#pragma unroll
                    for (int nt = 0; nt < 2; ++nt)
                        sa[mt][nt] = __builtin_amdgcn_mfma_f32_16x16x32_bf16(
                            af[mt][kh], bf[nt][kh], sa[mt][nt], 0, 0, 0);
            __builtin_amdgcn_s_setprio(0);
        }
        __builtin_amdgcn_s_barrier();  // all waves done reading As/Bs

        // ---- 2) exp + rowsum + P -> LDS (swizzled) ----
#pragma unroll
        for (int mt = 0; mt < 4; ++mt)
#pragma unroll
            for (int nt = 0; nt < 2; ++nt)
#pragma unroll
                for (int r = 0; r < 4; ++r) {
                    int prow = wm * 64 + mt * 16 + quad * 4 + r;
                    int pcol = wn * 32 + nt * 16 + ln;
                    float p = __expf(sa[mt][nt][r] * SCALE_QK - FIXED_M);
                    rs[mt][r] += p;
                    int cb = pcol >> 3;
                    PsU[prow * 128 + (((cb & 7) ^ (prow & 7)) | (cb & 8)) * 8 +
                        (pcol & 7)] = f2bf(p);
                }

        // ---- 3) PV: O += P @ vt[:, kvb:+128]^T, two 64-wide halves ----
#pragma unroll
        for (int kh2 = 0; kh2 < 2; ++kh2) {
            // stage vt half: 512 f-rows x 64 kv into smem[0..32767]
#pragma unroll
            for (int jj = 0; jj < 8; ++jj) {
                int chunk = w * 8 + jj;    // 64 chunks of 8 f-rows
                load_lds16(vt + (size_t)(chunk * 8 + srow) * S_LEN + kvb +
                               kh2 * 64 + scol,
                           &smem[chunk * 512]);
            }
            __syncthreads();               // vt landed + P writes visible
#pragma unroll
            for (int kh = 0; kh < 2; ++kh) {
                bf16x8 pa[4], pb[8];
#pragma unroll
                for (int mt = 0; mt < 4; ++mt) {
                    int arow = wm * 64 + mt * 16 + ln;
                    int cb = kh2 * 8 + kh * 4 + quad;
                    pa[mt] = *(const bf16x8*)&PsU[arow * 128 +
                        (((cb & 7) ^ (arow & 7)) | (cb & 8)) * 8];
                }
#pragma unroll
                for (int nt = 0; nt < 8; ++nt) {
                    int brow = wn * 128 + nt * 16 + ln;
                    pb[nt] = *(const bf16x8*)&smem[brow * 64 + (kh ? q1 : q0)];
                }
                __builtin_amdgcn_s_setprio(1);
#pragma unroll
                for (int mt = 0; mt < 4; ++mt)
#pragma unroll
                    for (int nt = 0; nt < 8; ++nt)
                        o[mt][nt] = __builtin_amdgcn_mfma_f32_16x16x32_bf16(
                            pa[mt], pb[nt], o[mt][nt], 0, 0, 0);
                __builtin_amdgcn_s_setprio(0);
            }
            __builtin_amdgcn_s_barrier();  // guard next stage clobber
        }
    }

    // ---- rowsum partials -> lpart[S][32], slot = split*4 + wn ----
#pragma unroll
    for (int mt = 0; mt < 4; ++mt)
#pragma unroll
        for (int r = 0; r < 4; ++r) {
            float v = rs[mt][r];
            v += __shfl_xor(v, 1);
            v += __shfl_xor(v, 2);
            v += __shfl_xor(v, 4);
            v += __shfl_xor(v, 8);
            if (ln == 0) {
                int row = m0 + wm * 64 + mt * 16 + quad * 4 + r;
                lpart[(size_t)row * 32 + split * 4 + wn] = v;
            }
        }

    // ---- O partial -> O_p[split] ----
    unsigned short* Op = O_p + (size_t)split * S_LEN * F_DIM;
#pragma unroll
    for (int mt = 0; mt < 4; ++mt)
#pragma unroll
        for (int nt = 0; nt < 8; ++nt)
#pragma unroll
            for (int r = 0; r < 4; ++r) {
                int row = m0 + wm * 64 + mt * 16 + quad * 4 + r;
                int col = wn * 128 + nt * 16 + ln;
                Op[(size_t)row * F_DIM + col] = f2bf(o[mt][nt][r]);
            }
}

// ======== legacy 128x128 K-loop (BK=64) — used by fused final gemm ========
#define GEMM_KLOOP(XPTR, LDX, WPTR, LDW, KBEG, KEND)                                  \
    for (int k0 = (KBEG); k0 < (KEND); k0 += 64) {                                    \
        __syncthreads();                                                              \
        _Pragma("unroll")                                                             \
        for (int i = 0; i < 2; ++i) {                                                 \
            int c = w * 2 + i;                                                        \
            _Pragma("unroll")                                                         \
            for (int kh = 0; kh < 2; ++kh) {                                          \
                load_lds16((XPTR) + (size_t)(m0 + c * 16 + ln) * (LDX) + k0 + kh * 32 + quad * 8, \
                           &As[(c * 2 + kh) * 512]);                                  \
                load_lds16((WPTR) + (size_t)(n0 + c * 16 + ln) * (LDW) + k0 + kh * 32 + quad * 8, \
                           &Bs[(c * 2 + kh) * 512]);                                  \
            }                                                                         \
        }                                                                             \
        __syncthreads();                                                              \
        _Pragma("unroll")                                                             \
        for (int kh = 0; kh < 2; ++kh) {                                              \
            bf16x8 af2[4], bfr2[4];                                                   \
            _Pragma("unroll")                                                         \
            for (int mt = 0; mt < 4; ++mt)                                            \
                af2[mt] = *(const bf16x8*)&As[((wr * 4 + mt) * 2 + kh) * 512 + l * 8]; \
            _Pragma("unroll")                                                         \
            for (int nt = 0; nt < 4; ++nt)                                            \
                bfr2[nt] = *(const bf16x8*)&Bs[((wc * 4 + nt) * 2 + kh) * 512 + l * 8]; \
            _Pragma("unroll")                                                         \
            for (int mt = 0; mt < 4; ++mt)                                            \
                _Pragma("unroll")                                                     \
                for (int nt = 0; nt < 4; ++nt)                                        \
                    acc[mt][nt] = __builtin_amdgcn_mfma_f32_16x16x32_bf16(            \
                        af2[mt], bfr2[nt], acc[mt][nt], 0, 0, 0);                     \
        }                                                                             \
    }

// ---------------- final projection, fused: out = relu(res @ Wo^T + bo), f32 ----------------
__launch_bounds__(256, 2)
__global__ void gemm_final(const unsigned short* __restrict__ X,   // res [S][F]
                           const unsigned short* __restrict__ W,   // Wo [F][F]
                           const float* __restrict__ bias,
                           float* __restrict__ out) {
    __shared__ __align__(16) unsigned short As[16 * 512];
    __shared__ __align__(16) unsigned short Bs[16 * 512];
    const int n0 = blockIdx.y * 128;
    const int m0 = blockIdx.x * 128;
    const int tid = threadIdx.x;
    const int w = tid >> 6, l = tid & 63, quad = l >> 4, ln = l & 15;
    const int wr = w >> 1, wc = w & 1;

    f32x4 acc[4][4];
    f32x4 zero4 = {0.f, 0.f, 0.f, 0.f};
#pragma unroll
    for (int i = 0; i < 4; ++i)
#pragma unroll
        for (int j = 0; j < 4; ++j) acc[i][j] = zero4;

    GEMM_KLOOP(X, F_DIM, W, F_DIM, 0, F_DIM)

#pragma unroll
    for (int mt = 0; mt < 4; ++mt)
#pragma unroll
        for (int nt = 0; nt < 4; ++nt)
#pragma unroll
            for (int r = 0; r < 4; ++r) {
                int row = m0 + wr * 64 + mt * 16 + quad * 4 + r;
                int col = n0 + wc * 64 + nt * 16 + ln;
                out[(size_t)row * F_DIM + col] =
                    fmaxf(acc[mt][nt][r] + bias[col], 0.f);
            }
}

// ---------------- combine: denom + q_att dot + split-sum + elementwise fusion ----------------
__global__ void combine_kernel(const unsigned short* __restrict__ O_p,
                               const float* __restrict__ lpart,   // [S][32]
                               const unsigned short* __restrict__ qq,
                               const unsigned short* __restrict__ qk,
                               const unsigned short* __restrict__ qv,
                               unsigned short* __restrict__ res_bf) {
    int row = blockIdx.x;
    int t = threadIdx.x;  // 128 threads = 2 waves
    int wv = t >> 6, l = t & 63;
    __shared__ float ws[4];

    ushort4 a = *(const ushort4*)(qq + (size_t)row * F_DIM + t * 4);
    ushort4 b = *(const ushort4*)(qk + (size_t)row * F_DIM + t * 4);
    float dotp = bf2f(a.x) * bf2f(b.x) + bf2f(a.y) * bf2f(b.y) +
                 bf2f(a.z) * bf2f(b.z) + bf2f(a.w) * bf2f(b.w);
    float lp = (t < 32) ? lpart[(size_t)row * 32 + t] : 0.f;
#pragma unroll
    for (int off = 32; off >= 1; off >>= 1) {
        dotp += __shfl_xor(dotp, off);
        lp += __shfl_xor(lp, off);
    }
    if (l == 0) { ws[wv] = dotp; ws[2 + wv] = lp; }
    __syncthreads();
    float qa = ws[0] + ws[1];
    float denom = __expf(qa * SCALE_QK - FIXED_M) + ws[2] + ws[3];
    float inv = 1.f / denom;

    // thread t handles f in [t*4, t*4+4)
    float4 s = {0.f, 0.f, 0.f, 0.f};
#pragma unroll
    for (int i = 0; i < PSPLIT; ++i) {
        ushort4 o = *(const ushort4*)(O_p + ((size_t)i * S_LEN + row) * F_DIM + t * 4);
        s.x += bf2f(o.x); s.y += bf2f(o.y); s.z += bf2f(o.z); s.w += bf2f(o.w);
    }
    ushort4 qvv = *(const ushort4*)(qv + (size_t)row * F_DIM + t * 4);
    ushort4 o;
    o.x = f2bf(bf2f(qvv.x) * qa + s.x * inv);
    o.y = f2bf(bf2f(qvv.y) * qa + s.y * inv);
    o.z = f2bf(bf2f(qvv.z) * qa + s.z * inv);
    o.w = f2bf(bf2f(qvv.w) * qa + s.w * inv);
    *(ushort4*)(res_bf + (size_t)row * F_DIM + t * 4) = o;
}

extern "C" void kernel_launch(void* const* d_in, const int* in_sizes, int n_in,
                              void* d_out, int out_size, void* d_ws, size_t ws_size,
                              hipStream_t stream) {
    const float* q  = (const float*)d_in[0];
    const float* k  = (const float*)d_in[1];
    const float* v  = (const float*)d_in[2];
    const float* Wq = (const float*)d_in[3];
    const float* bq = (const float*)d_in[4];
    const float* Wk = (const float*)d_in[5];
    const float* bk = (const float*)d_in[6];
    const float* Wv = (const float*)d_in[7];
    const float* bv = (const float*)d_in[8];
    const float* Wo = (const float*)d_in[9];
    const float* bo = (const float*)d_in[10];
    float* out = (float*)d_out;

    char* p = (char*)d_ws;
    auto alloc = [&](size_t bytes) -> char* {
        char* r = p; p += (bytes + 255) & ~(size_t)255; return r;
    };
    const size_t SF = (size_t)S_LEN * F_DIM;
    unsigned short* q_bf  = (unsigned short*)alloc(SF * 2);
    unsigned short* k_bf  = (unsigned short*)alloc(SF * 2);
    unsigned short* v_bf  = (unsigned short*)alloc(SF * 2);
    unsigned short* qq_bf = (unsigned short*)alloc(SF * 2);
    unsigned short* kk_bf = (unsigned short*)alloc(SF * 2);
    unsigned short* vv_bf = (unsigned short*)alloc(SF * 2);
    unsigned short* vt_bf = (unsigned short*)alloc(SF * 2);
    unsigned short* qk_bf = (unsigned short*)alloc(SF * 2);
    unsigned short* qv_bf = (unsigned short*)alloc(SF * 2);
    unsigned short* res_bf = (unsigned short*)alloc(SF * 2);
    unsigned short* wq_bf = (unsigned short*)alloc((size_t)F_DIM * F_DIM * 2);
    unsigned short* wk_bf = (unsigned short*)alloc((size_t)F_DIM * F_DIM * 2);
    unsigned short* wv_bf = (unsigned short*)alloc((size_t)F_DIM * F_DIM * 2);
    unsigned short* wo_bf = (unsigned short*)alloc((size_t)F_DIM * F_DIM * 2);
    float* lpart = (float*)alloc((size_t)S_LEN * 32 * 4);                        // [S][32]
    unsigned short* O_p = (unsigned short*)alloc((size_t)PSPLIT * SF * 2);      // 32 MB

    static int attr_done = 0;
    if (!attr_done) {
        hipFuncSetAttribute((const void*)gemm_proj2,
                            hipFuncAttributeMaxDynamicSharedMemorySize, 131072);
        hipFuncSetAttribute((const void*)gemm_fa,
                            hipFuncAttributeMaxDynamicSharedMemorySize, 131072);
        attr_done = 1;
    }

    CastArgs ca;
    ca.src[0] = q;  ca.dst[0] = q_bf;  ca.n4[0] = (int)(SF / 4);
    ca.src[1] = k;  ca.dst[1] = k_bf;  ca.n4[1] = (int)(SF / 4);
    ca.src[2] = v;  ca.dst[2] = v_bf;  ca.n4[2] = (int)(SF / 4);
    ca.src[3] = Wq; ca.dst[3] = wq_bf; ca.n4[3] = F_DIM * F_DIM / 4;
    ca.src[4] = Wk; ca.dst[4] = wk_bf; ca.n4[4] = F_DIM * F_DIM / 4;
    ca.src[5] = Wv; ca.dst[5] = wv_bf; ca.n4[5] = F_DIM * F_DIM / 4;
    ca.src[6] = Wo; ca.dst[6] = wo_bf; ca.n4[6] = F_DIM * F_DIM / 4;
    cast_all<<<dim3((unsigned)(SF / 4 / 256), 7), 256, 0, stream>>>(ca);

    GemmArgs ga;
    ga.d[0] = { q_bf, wq_bf, bq, qq_bf, nullptr, 1 };
    ga.d[1] = { k_bf, wk_bf, bk, kk_bf, nullptr, 1 };
    ga.d[2] = { v_bf, wv_bf, bv, vv_bf, nullptr, 1 };
    ga.d[3] = { q_bf, wk_bf, bk, qk_bf, nullptr, 0 };
    ga.d[4] = { q_bf, wv_bf, bv, qv_bf, nullptr, 0 };
    gemm_proj2<<<dim3(S_LEN / 256, 10), 512, 131072, stream>>>(ga);

    transpose_bf16<<<dim3(S_LEN / 64, F_DIM / 64), 256, 0, stream>>>(vv_bf, vt_bf);

    gemm_fa<<<dim3(256), 512, 131072, stream>>>(qq_bf, kk_bf, vt_bf, O_p, lpart);

    combine_kernel<<<S_LEN, 128, 0, stream>>>(O_p, lpart, qq_bf, qk_bf, qv_bf, res_bf);

    gemm_final<<<dim3(S_LEN / 128, 4), 256, 0, stream>>>(res_bf, wo_bf, bo, out);
}

// Round 9
// 202.110 us; speedup vs baseline: 1.2578x; 1.2578x over previous
//
#include <hip/hip_runtime.h>
#include <math.h>

#define S_LEN 4096
#define F_DIM 512
#define PSPLIT 8
#define FIXED_M 4.0f
#define SCALE_QK 0.04415108f   // 1/sqrt(513)

typedef __attribute__((ext_vector_type(8))) short bf16x8;
typedef __attribute__((ext_vector_type(4))) float f32x4;

__device__ __forceinline__ unsigned short f2bf(float x) {
    union { float f; unsigned u; } v; v.f = x;
    unsigned r = v.u + 0x7fffu + ((v.u >> 16) & 1u);
    return (unsigned short)(r >> 16);
}
__device__ __forceinline__ float bf2f(unsigned short b) {
    union { unsigned u; float f; } v; v.u = ((unsigned)b) << 16;
    return v.f;
}
__device__ __forceinline__ void load_lds16(const void* g, void* l) {
    __builtin_amdgcn_global_load_lds(
        (const __attribute__((address_space(1))) unsigned int*)g,
        (__attribute__((address_space(3))) unsigned int*)l, 16, 0, 0);
}

// ---------------- fused fp32 -> bf16 casts ----------------
struct CastArgs {
    const float* src[7];
    unsigned short* dst[7];
    int n4[7];
};
__global__ void cast_all(CastArgs a) {
    int r = blockIdx.y;
    int i = blockIdx.x * blockDim.x + threadIdx.x;
    if (i >= a.n4[r]) return;
    float4 v = ((const float4*)a.src[r])[i];
    ushort4 o;
    o.x = f2bf(v.x); o.y = f2bf(v.y); o.z = f2bf(v.z); o.w = f2bf(v.w);
    ((ushort4*)a.dst[r])[i] = o;
}

// ---------------- bf16 transpose: src [S][F] -> dst [F][S] ----------------
__global__ void transpose_bf16(const unsigned short* __restrict__ src,
                               unsigned short* __restrict__ dst) {
    __shared__ __align__(16) unsigned short tile[64][72];
    const int s0 = blockIdx.x * 64, f0 = blockIdx.y * 64;
    const int tid = threadIdx.x;
#pragma unroll
    for (int it = 0; it < 2; ++it) {
        int u = it * 256 + tid;
        int r = u >> 3, c = (u & 7) * 8;
        *(uint4*)&tile[r][c] = *(const uint4*)(src + (size_t)(s0 + r) * F_DIM + f0 + c);
    }
    __syncthreads();
#pragma unroll
    for (int it = 0; it < 2; ++it) {
        int u = it * 256 + tid;
        int fl = u >> 3, sc = (u & 7) * 8;
        unsigned short tmp[8];
#pragma unroll
        for (int i = 0; i < 8; ++i) tmp[i] = tile[sc + i][fl];
        *(uint4*)(dst + (size_t)(f0 + fl) * S_LEN + s0 + sc) = *(uint4*)tmp;
    }
}

struct GemmDesc {
    const unsigned short* X;
    const unsigned short* W;
    const float* bias;
    unsigned short* out_bf;
    float* out_f32;
    int relu;
};
struct GemmArgs { GemmDesc d[5]; };

// =====================================================================
// 256x256 8-phase K-loop (BK=64, K=512), 512 threads (8 waves, 2Mx4N),
// 128 KiB dynamic LDS (2 dbuf x [256x64] x {A,B}), XOR-swizzled layout.
// CHAMPION (measured 199.4 µs in Round 3): 16x16x32 MFMA, A staged at
// phase 0, B staged at phase 1, single per-K-tile vmcnt(0) at phase 3.
// Verified-failed variants (do not reintroduce): 32x32x16 MFMA (R2),
// both-stages-at-phase-0 (R7), XCD swizzle (R4, neutral), depth-2
// 3-buffer ring (R5), 128^2 m97 tile (R6), exp+pv fusion (R8).
//
// LDS layout per matrix chunk: row r (0..255), col-block q (0..7, 8 bf16
// = 16B each). Linear byte pos (r*128 + q*16) HOLDS global col-block
// (q ^ (r&7)).  global_load_lds writes base+lane*16 linearly, so the
// per-lane GLOBAL source col-block is (lane&7)^(lane>>3)  (rule #21).
// Read of A[r][cb] is lds[r*128 + ((cb)^(r&7))*16].
// =====================================================================
#define FRAGA(qm) { _Pragma("unroll") for (int mt = 0; mt < 4; ++mt) { \
    const int ro = (aw + (qm) * 64 + mt * 16) * 64 + rbase; \
    af[mt][0] = *(const bf16x8*)&Ac[ro + q0]; \
    af[mt][1] = *(const bf16x8*)&Ac[ro + q1]; } }

#define FRAGB(qn) { _Pragma("unroll") for (int nt = 0; nt < 2; ++nt) { \
    const int ro = (bw + (qn) * 32 + nt * 16) * 64 + rbase; \
    bf[nt][0] = *(const bf16x8*)&Bc[ro + q0]; \
    bf[nt][1] = *(const bf16x8*)&Bc[ro + q1]; } }

#define MMQ(qm, qn) { __builtin_amdgcn_s_setprio(1); \
    _Pragma("unroll") for (int kh = 0; kh < 2; ++kh) \
    _Pragma("unroll") for (int mt = 0; mt < 4; ++mt) \
    _Pragma("unroll") for (int nt = 0; nt < 2; ++nt) \
      acc[(qm) * 4 + mt][(qn) * 2 + nt] = __builtin_amdgcn_mfma_f32_16x16x32_bf16( \
          af[mt][kh], bf[nt][kh], acc[(qm) * 4 + mt][(qn) * 2 + nt], 0, 0, 0); \
    __builtin_amdgcn_s_setprio(0); }

__device__ __forceinline__ void kloop256(const unsigned short* __restrict__ A, int lda,
                                         const unsigned short* __restrict__ B, int ldb,
                                         int m0, int n0, int kbase,
                                         unsigned short* smem, f32x4 acc[8][4]) {
    const int tid = threadIdx.x;
    const int w = tid >> 6, l = tid & 63;
    const int ln = l & 15, quad = l >> 4, lnx = l & 7;
    const int wm = w >> 2, wn = w & 3;
    const int srow = l >> 3;                 // 0..7 (row within 8-row chunk)
    const int scol = (lnx ^ srow) * 8;       // pre-swizzled global col-block
    const int rbase = ln * 64;               // row offset in ushorts
    const int q0 = (quad ^ lnx) * 8;         // kh=0 swizzled read offset
    const int q1 = ((4 + quad) ^ lnx) * 8;   // kh=1
    unsigned short* As = smem;               // 2 x 16384 ushorts
    unsigned short* Bs = smem + 32768;       // 2 x 16384 ushorts
    const unsigned short* Asrc = A + (size_t)(m0 + srow) * lda + kbase + scol;
    const unsigned short* Bsrc = B + (size_t)(n0 + srow) * ldb + kbase + scol;

    auto stageA = [&](int dd, int ktn) {
#pragma unroll
        for (int j = 0; j < 4; ++j) {
            int chunk = w * 4 + j;           // wave-uniform: 8 rows per instr
            load_lds16(Asrc + (size_t)(chunk * 8) * lda + ktn * 64,
                       &As[dd * 16384 + chunk * 512]);
        }
    };
    auto stageB = [&](int dd, int ktn) {
#pragma unroll
        for (int j = 0; j < 4; ++j) {
            int chunk = w * 4 + j;
            load_lds16(Bsrc + (size_t)(chunk * 8) * ldb + ktn * 64,
                       &Bs[dd * 16384 + chunk * 512]);
        }
    };

    // prologue: stage K-tile 0, drain, barrier
    stageA(0, 0); stageB(0, 0);
    asm volatile("s_waitcnt vmcnt(0)" ::: "memory");
    __builtin_amdgcn_s_barrier();

#pragma unroll
    for (int kt = 0; kt < 8; ++kt) {
        const int d = kt & 1;
        const unsigned short* Ac = &As[d * 16384];
        const unsigned short* Bc = &Bs[d * 16384];
        const int aw = wm * 128, bw = wn * 64;
        bf16x8 af[4][2], bf[2][2];

        // phase 0: quadrant (0,0); prefetch A of kt+1
        FRAGA(0); FRAGB(0);
        if (kt < 7) stageA(d ^ 1, kt + 1);
        __builtin_amdgcn_s_barrier();
        MMQ(0, 0);
        __builtin_amdgcn_s_barrier();

        // phase 1: quadrant (0,1); prefetch B of kt+1
        FRAGB(1);
        if (kt < 7) stageB(d ^ 1, kt + 1);
        __builtin_amdgcn_s_barrier();
        MMQ(0, 1);
        __builtin_amdgcn_s_barrier();

        // phase 2: quadrant (1,1)
        FRAGA(1);
        __builtin_amdgcn_s_barrier();
        MMQ(1, 1);
        __builtin_amdgcn_s_barrier();

        // phase 3: quadrant (1,0); single per-K-tile vmcnt wait
        FRAGB(0);
        __builtin_amdgcn_s_barrier();
        MMQ(1, 0);
        asm volatile("s_waitcnt vmcnt(0)" ::: "memory");
        __builtin_amdgcn_s_barrier();
    }
}

// ---------------- projections: out = op(X @ W^T + b), 5 gemms ----------------
__launch_bounds__(512, 2)
__global__ void gemm_proj2(GemmArgs args) {
    extern __shared__ unsigned short smem[];
    const GemmDesc d = args.d[blockIdx.y >> 1];
    const int n0 = (blockIdx.y & 1) * 256;
    const int m0 = blockIdx.x * 256;
    f32x4 acc[8][4];
    f32x4 z = {0.f, 0.f, 0.f, 0.f};
#pragma unroll
    for (int i = 0; i < 8; ++i)
#pragma unroll
        for (int j = 0; j < 4; ++j) acc[i][j] = z;

    kloop256(d.X, F_DIM, d.W, F_DIM, m0, n0, 0, smem, acc);

    const int tid = threadIdx.x;
    const int w = tid >> 6, l = tid & 63, quad = l >> 4, ln = l & 15;
    const int wm = w >> 2, wn = w & 3;
#pragma unroll
    for (int mi = 0; mi < 8; ++mi)
#pragma unroll
        for (int ni = 0; ni < 4; ++ni)
#pragma unroll
            for (int r = 0; r < 4; ++r) {
                int row = m0 + wm * 128 + mi * 16 + quad * 4 + r;
                int col = n0 + wn * 64 + ni * 16 + ln;
                float vv = acc[mi][ni][r] + d.bias[col];
                if (d.relu) vv = fmaxf(vv, 0.f);
                if (d.out_bf)  d.out_bf[(size_t)row * F_DIM + col] = f2bf(vv);
                if (d.out_f32) d.out_f32[(size_t)row * F_DIM + col] = vv;
            }
}

// ---------------- P = exp(scale*(qq @ kk^T) - M) + row-sum partials ----------------
__launch_bounds__(512, 2)
__global__ void gemm_exp2(const unsigned short* __restrict__ X,   // qq [S][F]
                          const unsigned short* __restrict__ W,   // kk [S][F]
                          unsigned short* __restrict__ P,         // [S][S]
                          float* __restrict__ lpart) {            // [S][64]
    extern __shared__ unsigned short smem[];
    const int m0 = blockIdx.x * 256, n0 = blockIdx.y * 256;
    f32x4 acc[8][4];
    f32x4 z = {0.f, 0.f, 0.f, 0.f};
#pragma unroll
    for (int i = 0; i < 8; ++i)
#pragma unroll
        for (int j = 0; j < 4; ++j) acc[i][j] = z;

    kloop256(X, F_DIM, W, F_DIM, m0, n0, 0, smem, acc);

    const int tid = threadIdx.x;
    const int w = tid >> 6, l = tid & 63, quad = l >> 4, ln = l & 15;
    const int wm = w >> 2, wn = w & 3;
#pragma unroll
    for (int mi = 0; mi < 8; ++mi)
#pragma unroll
        for (int r = 0; r < 4; ++r) {
            int row = m0 + wm * 128 + mi * 16 + quad * 4 + r;
            float rs = 0.f;
#pragma unroll
            for (int ni = 0; ni < 4; ++ni) {
                int col = n0 + wn * 64 + ni * 16 + ln;
                float p = __expf(acc[mi][ni][r] * SCALE_QK - FIXED_M);
                P[(size_t)row * S_LEN + col] = f2bf(p);
                rs += p;
            }
            rs += __shfl_xor(rs, 1);
            rs += __shfl_xor(rs, 2);
            rs += __shfl_xor(rs, 4);
            rs += __shfl_xor(rs, 8);
            if (ln == 0) lpart[(size_t)row * 64 + blockIdx.y * 4 + wn] = rs;
        }
}

// ---------------- O_p[split] = P[:, ks] @ vt[:, ks]^T (bf16 partials) ----------------
__launch_bounds__(512, 2)
__global__ void gemm_pv2(const unsigned short* __restrict__ P,   // [S][S]
                         const unsigned short* __restrict__ vt,  // [F][S]
                         unsigned short* __restrict__ O_p) {     // [PSPLIT][S][F]
    extern __shared__ unsigned short smem[];
    const int nb = blockIdx.y & 1, split = blockIdx.y >> 1;
    const int m0 = blockIdx.x * 256, n0 = nb * 256;
    f32x4 acc[8][4];
    f32x4 z = {0.f, 0.f, 0.f, 0.f};
#pragma unroll
    for (int i = 0; i < 8; ++i)
#pragma unroll
        for (int j = 0; j < 4; ++j) acc[i][j] = z;

    kloop256(P, S_LEN, vt, S_LEN, m0, n0, split * (S_LEN / PSPLIT), smem, acc);

    unsigned short* Op = O_p + (size_t)split * S_LEN * F_DIM;
    const int tid = threadIdx.x;
    const int w = tid >> 6, l = tid & 63, quad = l >> 4, ln = l & 15;
    const int wm = w >> 2, wn = w & 3;
#pragma unroll
    for (int mi = 0; mi < 8; ++mi)
#pragma unroll
        for (int ni = 0; ni < 4; ++ni)
#pragma unroll
            for (int r = 0; r < 4; ++r) {
                int row = m0 + wm * 128 + mi * 16 + quad * 4 + r;
                int col = n0 + wn * 64 + ni * 16 + ln;
                Op[(size_t)row * F_DIM + col] = f2bf(acc[mi][ni][r]);
            }
}

// ======== legacy 128x128 K-loop (BK=64) — used by fused final gemm ========
#define GEMM_KLOOP(XPTR, LDX, WPTR, LDW, KBEG, KEND)                                  \
    for (int k0 = (KBEG); k0 < (KEND); k0 += 64) {                                    \
        __syncthreads();                                                              \
        _Pragma("unroll")                                                             \
        for (int i = 0; i < 2; ++i) {                                                 \
            int c = w * 2 + i;                                                        \
            _Pragma("unroll")                                                         \
            for (int kh = 0; kh < 2; ++kh) {                                          \
                load_lds16((XPTR) + (size_t)(m0 + c * 16 + ln) * (LDX) + k0 + kh * 32 + quad * 8, \
                           &As[(c * 2 + kh) * 512]);                                  \
                load_lds16((WPTR) + (size_t)(n0 + c * 16 + ln) * (LDW) + k0 + kh * 32 + quad * 8, \
                           &Bs[(c * 2 + kh) * 512]);                                  \
            }                                                                         \
        }                                                                             \
        __syncthreads();                                                              \
        _Pragma("unroll")                                                             \
        for (int kh = 0; kh < 2; ++kh) {                                              \
            bf16x8 af2[4], bfr2[4];                                                   \
            _Pragma("unroll")                                                         \
            for (int mt = 0; mt < 4; ++mt)                                            \
                af2[mt] = *(const bf16x8*)&As[((wr * 4 + mt) * 2 + kh) * 512 + l * 8]; \
            _Pragma("unroll")                                                         \
            for (int nt = 0; nt < 4; ++nt)                                            \
                bfr2[nt] = *(const bf16x8*)&Bs[((wc * 4 + nt) * 2 + kh) * 512 + l * 8]; \
            _Pragma("unroll")                                                         \
            for (int mt = 0; mt < 4; ++mt)                                            \
                _Pragma("unroll")                                                     \
                for (int nt = 0; nt < 4; ++nt)                                        \
                    acc[mt][nt] = __builtin_amdgcn_mfma_f32_16x16x32_bf16(            \
                        af2[mt], bfr2[nt], acc[mt][nt], 0, 0, 0);                     \
        }                                                                             \
    }

// ---------------- final projection, fused: out = relu(res @ Wo^T + bo), f32 ----------------
__launch_bounds__(256, 2)
__global__ void gemm_final(const unsigned short* __restrict__ X,   // res [S][F]
                           const unsigned short* __restrict__ W,   // Wo [F][F]
                           const float* __restrict__ bias,
                           float* __restrict__ out) {
    __shared__ __align__(16) unsigned short As[16 * 512];
    __shared__ __align__(16) unsigned short Bs[16 * 512];
    const int n0 = blockIdx.y * 128;
    const int m0 = blockIdx.x * 128;
    const int tid = threadIdx.x;
    const int w = tid >> 6, l = tid & 63, quad = l >> 4, ln = l & 15;
    const int wr = w >> 1, wc = w & 1;

    f32x4 acc[4][4];
    f32x4 zero4 = {0.f, 0.f, 0.f, 0.f};
#pragma unroll
    for (int i = 0; i < 4; ++i)
#pragma unroll
        for (int j = 0; j < 4; ++j) acc[i][j] = zero4;

    GEMM_KLOOP(X, F_DIM, W, F_DIM, 0, F_DIM)

#pragma unroll
    for (int mt = 0; mt < 4; ++mt)
#pragma unroll
        for (int nt = 0; nt < 4; ++nt)
#pragma unroll
            for (int r = 0; r < 4; ++r) {
                int row = m0 + wr * 64 + mt * 16 + quad * 4 + r;
                int col = n0 + wc * 64 + nt * 16 + ln;
                out[(size_t)row * F_DIM + col] =
                    fmaxf(acc[mt][nt][r] + bias[col], 0.f);
            }
}

// ---------------- combine: denom + q_att dot + split-sum + elementwise fusion ----------------
__global__ void combine_kernel(const unsigned short* __restrict__ O_p,
                               const float* __restrict__ lpart,   // [S][64]
                               const unsigned short* __restrict__ qq,
                               const unsigned short* __restrict__ qk,
                               const unsigned short* __restrict__ qv,
                               unsigned short* __restrict__ res_bf) {
    int row = blockIdx.x;
    int t = threadIdx.x;  // 128 threads = 2 waves
    int wv = t >> 6, l = t & 63;
    __shared__ float ws[4];

    ushort4 a = *(const ushort4*)(qq + (size_t)row * F_DIM + t * 4);
    ushort4 b = *(const ushort4*)(qk + (size_t)row * F_DIM + t * 4);
    float dotp = bf2f(a.x) * bf2f(b.x) + bf2f(a.y) * bf2f(b.y) +
                 bf2f(a.z) * bf2f(b.z) + bf2f(a.w) * bf2f(b.w);
    float lp = (t < 64) ? lpart[(size_t)row * 64 + t] : 0.f;
#pragma unroll
    for (int off = 32; off >= 1; off >>= 1) {
        dotp += __shfl_xor(dotp, off);
        lp += __shfl_xor(lp, off);
    }
    if (l == 0) { ws[wv] = dotp; ws[2 + wv] = lp; }
    __syncthreads();
    float qa = ws[0] + ws[1];
    float denom = __expf(qa * SCALE_QK - FIXED_M) + ws[2] + ws[3];
    float inv = 1.f / denom;

    // thread t handles f in [t*4, t*4+4)
    float4 s = {0.f, 0.f, 0.f, 0.f};
#pragma unroll
    for (int i = 0; i < PSPLIT; ++i) {
        ushort4 o = *(const ushort4*)(O_p + ((size_t)i * S_LEN + row) * F_DIM + t * 4);
        s.x += bf2f(o.x); s.y += bf2f(o.y); s.z += bf2f(o.z); s.w += bf2f(o.w);
    }
    ushort4 qvv = *(const ushort4*)(qv + (size_t)row * F_DIM + t * 4);
    ushort4 o;
    o.x = f2bf(bf2f(qvv.x) * qa + s.x * inv);
    o.y = f2bf(bf2f(qvv.y) * qa + s.y * inv);
    o.z = f2bf(bf2f(qvv.z) * qa + s.z * inv);
    o.w = f2bf(bf2f(qvv.w) * qa + s.w * inv);
    *(ushort4*)(res_bf + (size_t)row * F_DIM + t * 4) = o;
}

extern "C" void kernel_launch(void* const* d_in, const int* in_sizes, int n_in,
                              void* d_out, int out_size, void* d_ws, size_t ws_size,
                              hipStream_t stream) {
    const float* q  = (const float*)d_in[0];
    const float* k  = (const float*)d_in[1];
    const float* v  = (const float*)d_in[2];
    const float* Wq = (const float*)d_in[3];
    const float* bq = (const float*)d_in[4];
    const float* Wk = (const float*)d_in[5];
    const float* bk = (const float*)d_in[6];
    const float* Wv = (const float*)d_in[7];
    const float* bv = (const float*)d_in[8];
    const float* Wo = (const float*)d_in[9];
    const float* bo = (const float*)d_in[10];
    float* out = (float*)d_out;

    char* p = (char*)d_ws;
    auto alloc = [&](size_t bytes) -> char* {
        char* r = p; p += (bytes + 255) & ~(size_t)255; return r;
    };
    const size_t SF = (size_t)S_LEN * F_DIM;
    unsigned short* q_bf  = (unsigned short*)alloc(SF * 2);
    unsigned short* k_bf  = (unsigned short*)alloc(SF * 2);
    unsigned short* v_bf  = (unsigned short*)alloc(SF * 2);
    unsigned short* qq_bf = (unsigned short*)alloc(SF * 2);
    unsigned short* kk_bf = (unsigned short*)alloc(SF * 2);
    unsigned short* vv_bf = (unsigned short*)alloc(SF * 2);
    unsigned short* vt_bf = (unsigned short*)alloc(SF * 2);
    unsigned short* qk_bf = (unsigned short*)alloc(SF * 2);
    unsigned short* qv_bf = (unsigned short*)alloc(SF * 2);
    unsigned short* res_bf = (unsigned short*)alloc(SF * 2);
    unsigned short* wq_bf = (unsigned short*)alloc((size_t)F_DIM * F_DIM * 2);
    unsigned short* wk_bf = (unsigned short*)alloc((size_t)F_DIM * F_DIM * 2);
    unsigned short* wv_bf = (unsigned short*)alloc((size_t)F_DIM * F_DIM * 2);
    unsigned short* wo_bf = (unsigned short*)alloc((size_t)F_DIM * F_DIM * 2);
    unsigned short* P_bf  = (unsigned short*)alloc((size_t)S_LEN * S_LEN * 2);  // 33.5 MB
    float* lpart = (float*)alloc((size_t)S_LEN * 64 * 4);                        // [S][64]
    unsigned short* O_p = (unsigned short*)alloc((size_t)PSPLIT * SF * 2);      // 32 MB

    static int attr_done = 0;
    if (!attr_done) {
        hipFuncSetAttribute((const void*)gemm_proj2,
                            hipFuncAttributeMaxDynamicSharedMemorySize, 131072);
        hipFuncSetAttribute((const void*)gemm_exp2,
                            hipFuncAttributeMaxDynamicSharedMemorySize, 131072);
        hipFuncSetAttribute((const void*)gemm_pv2,
                            hipFuncAttributeMaxDynamicSharedMemorySize, 131072);
        attr_done = 1;
    }

    CastArgs ca;
    ca.src[0] = q;  ca.dst[0] = q_bf;  ca.n4[0] = (int)(SF / 4);
    ca.src[1] = k;  ca.dst[1] = k_bf;  ca.n4[1] = (int)(SF / 4);
    ca.src[2] = v;  ca.dst[2] = v_bf;  ca.n4[2] = (int)(SF / 4);
    ca.src[3] = Wq; ca.dst[3] = wq_bf; ca.n4[3] = F_DIM * F_DIM / 4;
    ca.src[4] = Wk; ca.dst[4] = wk_bf; ca.n4[4] = F_DIM * F_DIM / 4;
    ca.src[5] = Wv; ca.dst[5] = wv_bf; ca.n4[5] = F_DIM * F_DIM / 4;
    ca.src[6] = Wo; ca.dst[6] = wo_bf; ca.n4[6] = F_DIM * F_DIM / 4;
    cast_all<<<dim3((unsigned)(SF / 4 / 256), 7), 256, 0, stream>>>(ca);

    GemmArgs ga;
    ga.d[0] = { q_bf, wq_bf, bq, qq_bf, nullptr, 1 };
    ga.d[1] = { k_bf, wk_bf, bk, kk_bf, nullptr, 1 };
    ga.d[2] = { v_bf, wv_bf, bv, vv_bf, nullptr, 1 };
    ga.d[3] = { q_bf, wk_bf, bk, qk_bf, nullptr, 0 };
    ga.d[4] = { q_bf, wv_bf, bv, qv_bf, nullptr, 0 };
    gemm_proj2<<<dim3(S_LEN / 256, 10), 512, 131072, stream>>>(ga);

    transpose_bf16<<<dim3(S_LEN / 64, F_DIM / 64), 256, 0, stream>>>(vv_bf, vt_bf);

    gemm_exp2<<<dim3(S_LEN / 256, S_LEN / 256), 512, 131072, stream>>>(qq_bf, kk_bf, P_bf, lpart);

    gemm_pv2<<<dim3(S_LEN / 256, 2 * PSPLIT), 512, 131072, stream>>>(P_bf, vt_bf, O_p);

    combine_kernel<<<S_LEN, 128, 0, stream>>>(O_p, lpart, qq_bf, qk_bf, qv_bf, res_bf);

    gemm_final<<<dim3(S_LEN / 128, 4), 256, 0, stream>>>(res_bf, wo_bf, bo, out);
}

// Round 10
// 198.866 us; speedup vs baseline: 1.2783x; 1.0163x over previous
//
#include <hip/hip_runtime.h>
#include <math.h>

#define S_LEN 4096
#define F_DIM 512
#define PSPLIT 8
#define FIXED_M 4.0f
#define SCALE_QK 0.04415108f   // 1/sqrt(513)

typedef __attribute__((ext_vector_type(8))) short bf16x8;
typedef __attribute__((ext_vector_type(4))) float f32x4;

__device__ __forceinline__ unsigned short f2bf(float x) {
    union { float f; unsigned u; } v; v.f = x;
    unsigned r = v.u + 0x7fffu + ((v.u >> 16) & 1u);
    return (unsigned short)(r >> 16);
}
__device__ __forceinline__ float bf2f(unsigned short b) {
    union { unsigned u; float f; } v; v.u = ((unsigned)b) << 16;
    return v.f;
}
__device__ __forceinline__ void load_lds16(const void* g, void* l) {
    __builtin_amdgcn_global_load_lds(
        (const __attribute__((address_space(1))) unsigned int*)g,
        (__attribute__((address_space(3))) unsigned int*)l, 16, 0, 0);
}

// ---------------- fused fp32 -> bf16 casts ----------------
struct CastArgs {
    const float* src[7];
    unsigned short* dst[7];
    int n4[7];
};
__global__ void cast_all(CastArgs a) {
    int r = blockIdx.y;
    int i = blockIdx.x * blockDim.x + threadIdx.x;
    if (i >= a.n4[r]) return;
    float4 v = ((const float4*)a.src[r])[i];
    ushort4 o;
    o.x = f2bf(v.x); o.y = f2bf(v.y); o.z = f2bf(v.z); o.w = f2bf(v.w);
    ((ushort4*)a.dst[r])[i] = o;
}

// ---------------- bf16 transpose: src [S][F] -> dst [F][S] ----------------
__global__ void transpose_bf16(const unsigned short* __restrict__ src,
                               unsigned short* __restrict__ dst) {
    __shared__ __align__(16) unsigned short tile[64][72];
    const int s0 = blockIdx.x * 64, f0 = blockIdx.y * 64;
    const int tid = threadIdx.x;
#pragma unroll
    for (int it = 0; it < 2; ++it) {
        int u = it * 256 + tid;
        int r = u >> 3, c = (u & 7) * 8;
        *(uint4*)&tile[r][c] = *(const uint4*)(src + (size_t)(s0 + r) * F_DIM + f0 + c);
    }
    __syncthreads();
#pragma unroll
    for (int it = 0; it < 2; ++it) {
        int u = it * 256 + tid;
        int fl = u >> 3, sc = (u & 7) * 8;
        unsigned short tmp[8];
#pragma unroll
        for (int i = 0; i < 8; ++i) tmp[i] = tile[sc + i][fl];
        *(uint4*)(dst + (size_t)(f0 + fl) * S_LEN + s0 + sc) = *(uint4*)tmp;
    }
}

struct GemmDesc {
    const unsigned short* X;
    const unsigned short* W;
    const float* bias;
    unsigned short* out_bf;
    float* out_f32;
    int relu;
};
struct GemmArgs { GemmDesc d[5]; };

// =====================================================================
// 256x256 K-loop (BK=64, K=512), 512 threads (8 waves, 2Mx4N), 128 KiB
// LDS (2 dbuf x [256x64] x {A,B}), XOR-swizzled layout. Round-10 change
// vs the 199.4 champion: TRUE COUNTED VMCNT (T4, m218: counted vs
// drain-0 = +38-73%). Staging for tile t+1 is split into 4 pairs in
// CONSUMPTION ORDER, issued one pair per phase of tile t:
//   pair1 A-qm0 (chunks {w,16+w})      -> needed at t+1 phase 0
//   pair2 B-qn0 ({(2w&3)+8(w>>1),+1})  -> needed at t+1 phase 0 (+3 reuse)
//   pair3 B-qn1 (pair2 chunks +4)      -> needed at t+1 phase 1
//   pair4 A-qm1 ({8+w,24+w})           -> needed at t+1 phase 2
// Steady-state waits: vmcnt(6) at phases 0/1/2 (retire exactly the pair
// needed, issued >=4 phases ago), NO wait at phase 3 — the newest 6
// loads always stay in flight across barriers. Epilogue kt=7: 4 -> 2 -> 0.
// Buffer safety: t+2's writes to buffer d issue during t+1, after tile
// t's last read of d (end-of-t barrier). Per-wave vmcnt + barrier =>
// globally complete (m201 derived-waits discipline).
//
// LDS layout/swizzle unchanged (rule #21): linear byte (r*128+q*16)
// holds global col-block q^(r&7); per-lane source col-block
// (lane&7)^(lane>>3); reads XOR back with (row&7).
// =====================================================================
#define FRAGA(qm) { _Pragma("unroll") for (int mt = 0; mt < 4; ++mt) { \
    const int ro = (aw + (qm) * 64 + mt * 16) * 64 + rbase; \
    af[mt][0] = *(const bf16x8*)&Ac[ro + q0]; \
    af[mt][1] = *(const bf16x8*)&Ac[ro + q1]; } }

#define FRAGB(qn) { _Pragma("unroll") for (int nt = 0; nt < 2; ++nt) { \
    const int ro = (bw + (qn) * 32 + nt * 16) * 64 + rbase; \
    bf[nt][0] = *(const bf16x8*)&Bc[ro + q0]; \
    bf[nt][1] = *(const bf16x8*)&Bc[ro + q1]; } }

#define MMQ(qm, qn) { __builtin_amdgcn_s_setprio(1); \
    _Pragma("unroll") for (int kh = 0; kh < 2; ++kh) \
    _Pragma("unroll") for (int mt = 0; mt < 4; ++mt) \
    _Pragma("unroll") for (int nt = 0; nt < 2; ++nt) \
      acc[(qm) * 4 + mt][(qn) * 2 + nt] = __builtin_amdgcn_mfma_f32_16x16x32_bf16( \
          af[mt][kh], bf[nt][kh], acc[(qm) * 4 + mt][(qn) * 2 + nt], 0, 0, 0); \
    __builtin_amdgcn_s_setprio(0); }

__device__ __forceinline__ void kloop256(const unsigned short* __restrict__ A, int lda,
                                         const unsigned short* __restrict__ B, int ldb,
                                         int m0, int n0, int kbase,
                                         unsigned short* smem, f32x4 acc[8][4]) {
    const int tid = threadIdx.x;
    const int w = tid >> 6, l = tid & 63;
    const int ln = l & 15, quad = l >> 4, lnx = l & 7;
    const int wm = w >> 2, wn = w & 3;
    const int srow = l >> 3;                 // 0..7 (row within 8-row chunk)
    const int scol = (lnx ^ srow) * 8;       // pre-swizzled global col-block
    const int rbase = ln * 64;               // row offset in ushorts
    const int q0 = (quad ^ lnx) * 8;         // kh=0 swizzled read offset
    const int q1 = ((4 + quad) ^ lnx) * 8;   // kh=1
    unsigned short* As = smem;               // 2 x 16384 ushorts
    unsigned short* Bs = smem + 32768;       // 2 x 16384 ushorts
    const unsigned short* Asrc = A + (size_t)(m0 + srow) * lda + kbase + scol;
    const unsigned short* Bsrc = B + (size_t)(n0 + srow) * ldb + kbase + scol;

    // consumption-ordered chunk assignment (union over 8 waves = 0..31
    // exactly once per matrix; pair-k covers precisely the rows FRAG
    // reads at phase k — verified in derivation)
    const int a0c0 = w, a0c1 = 16 + w;                       // A-qm0
    const int a1c0 = 8 + w, a1c1 = 24 + w;                   // A-qm1
    const int b0c0 = ((2 * w) & 3) + 8 * (w >> 1);           // B-qn0
    const int b0c1 = b0c0 + 1;
    const int b1c0 = b0c0 + 4, b1c1 = b0c1 + 4;              // B-qn1

    auto stA = [&](int dd, int ktn, int c) {
        load_lds16(Asrc + (size_t)(c * 8) * lda + ktn * 64,
                   &As[dd * 16384 + c * 512]);
    };
    auto stB = [&](int dd, int ktn, int c) {
        load_lds16(Bsrc + (size_t)(c * 8) * ldb + ktn * 64,
                   &Bs[dd * 16384 + c * 512]);
    };

    // prologue: tile 0 fully staged (pair order), drain once, barrier
    stA(0, 0, a0c0); stA(0, 0, a0c1);
    stB(0, 0, b0c0); stB(0, 0, b0c1);
    stB(0, 0, b1c0); stB(0, 0, b1c1);
    stA(0, 0, a1c0); stA(0, 0, a1c1);
    asm volatile("s_waitcnt vmcnt(0)" ::: "memory");
    __builtin_amdgcn_s_barrier();

#pragma unroll
    for (int kt = 0; kt < 8; ++kt) {
        const int d = kt & 1;
        const unsigned short* Ac = &As[d * 16384];
        const unsigned short* Bc = &Bs[d * 16384];
        const int aw = wm * 128, bw = wn * 64;
        bf16x8 af[4][2], bf[2][2];

        // ---- phase 0: quadrant (0,0); issue pair1 (A-qm0) of kt+1 ----
        if (kt < 7) { stA(d ^ 1, kt + 1, a0c0); stA(d ^ 1, kt + 1, a0c1); }
        if (kt >= 1 && kt < 7) { asm volatile("s_waitcnt vmcnt(6)" ::: "memory"); }
        if (kt == 7)           { asm volatile("s_waitcnt vmcnt(4)" ::: "memory"); }
        __builtin_amdgcn_s_barrier();
        FRAGA(0); FRAGB(0);
        MMQ(0, 0);
        __builtin_amdgcn_s_barrier();

        // ---- phase 1: quadrant (0,1); issue pair2 (B-qn0) of kt+1 ----
        if (kt < 7) { stB(d ^ 1, kt + 1, b0c0); stB(d ^ 1, kt + 1, b0c1); }
        if (kt >= 1 && kt < 7) { asm volatile("s_waitcnt vmcnt(6)" ::: "memory"); }
        if (kt == 7)           { asm volatile("s_waitcnt vmcnt(2)" ::: "memory"); }
        __builtin_amdgcn_s_barrier();
        FRAGB(1);
        MMQ(0, 1);
        __builtin_amdgcn_s_barrier();

        // ---- phase 2: quadrant (1,1); issue pair3 (B-qn1) of kt+1 ----
        if (kt < 7) { stB(d ^ 1, kt + 1, b1c0); stB(d ^ 1, kt + 1, b1c1); }
        if (kt >= 1 && kt < 7) { asm volatile("s_waitcnt vmcnt(6)" ::: "memory"); }
        if (kt == 7)           { asm volatile("s_waitcnt vmcnt(0)" ::: "memory"); }
        __builtin_amdgcn_s_barrier();
        FRAGA(1);
        MMQ(1, 1);
        __builtin_amdgcn_s_barrier();

        // ---- phase 3: quadrant (1,0); issue pair4 (A-qm1); NO wait ----
        if (kt < 7) { stA(d ^ 1, kt + 1, a1c0); stA(d ^ 1, kt + 1, a1c1); }
        __builtin_amdgcn_s_barrier();
        FRAGB(0);   // re-read pair2 region of buffer d (waited at phase 0)
        MMQ(1, 0);
        __builtin_amdgcn_s_barrier();
    }
}

// ---------------- projections: out = op(X @ W^T + b), 5 gemms ----------------
__launch_bounds__(512, 2)
__global__ void gemm_proj2(GemmArgs args) {
    extern __shared__ unsigned short smem[];
    const GemmDesc d = args.d[blockIdx.y >> 1];
    const int n0 = (blockIdx.y & 1) * 256;
    const int m0 = blockIdx.x * 256;
    f32x4 acc[8][4];
    f32x4 z = {0.f, 0.f, 0.f, 0.f};
#pragma unroll
    for (int i = 0; i < 8; ++i)
#pragma unroll
        for (int j = 0; j < 4; ++j) acc[i][j] = z;

    kloop256(d.X, F_DIM, d.W, F_DIM, m0, n0, 0, smem, acc);

    const int tid = threadIdx.x;
    const int w = tid >> 6, l = tid & 63, quad = l >> 4, ln = l & 15;
    const int wm = w >> 2, wn = w & 3;
#pragma unroll
    for (int mi = 0; mi < 8; ++mi)
#pragma unroll
        for (int ni = 0; ni < 4; ++ni)
#pragma unroll
            for (int r = 0; r < 4; ++r) {
                int row = m0 + wm * 128 + mi * 16 + quad * 4 + r;
                int col = n0 + wn * 64 + ni * 16 + ln;
                float vv = acc[mi][ni][r] + d.bias[col];
                if (d.relu) vv = fmaxf(vv, 0.f);
                if (d.out_bf)  d.out_bf[(size_t)row * F_DIM + col] = f2bf(vv);
                if (d.out_f32) d.out_f32[(size_t)row * F_DIM + col] = vv;
            }
}

// ---------------- P = exp(scale*(qq @ kk^T) - M) + row-sum partials ----------------
__launch_bounds__(512, 2)
__global__ void gemm_exp2(const unsigned short* __restrict__ X,   // qq [S][F]
                          const unsigned short* __restrict__ W,   // kk [S][F]
                          unsigned short* __restrict__ P,         // [S][S]
                          float* __restrict__ lpart) {            // [S][64]
    extern __shared__ unsigned short smem[];
    const int m0 = blockIdx.x * 256, n0 = blockIdx.y * 256;
    f32x4 acc[8][4];
    f32x4 z = {0.f, 0.f, 0.f, 0.f};
#pragma unroll
    for (int i = 0; i < 8; ++i)
#pragma unroll
        for (int j = 0; j < 4; ++j) acc[i][j] = z;

    kloop256(X, F_DIM, W, F_DIM, m0, n0, 0, smem, acc);

    const int tid = threadIdx.x;
    const int w = tid >> 6, l = tid & 63, quad = l >> 4, ln = l & 15;
    const int wm = w >> 2, wn = w & 3;
#pragma unroll
    for (int mi = 0; mi < 8; ++mi)
#pragma unroll
        for (int r = 0; r < 4; ++r) {
            int row = m0 + wm * 128 + mi * 16 + quad * 4 + r;
            float rs = 0.f;
#pragma unroll
            for (int ni = 0; ni < 4; ++ni) {
                int col = n0 + wn * 64 + ni * 16 + ln;
                float p = __expf(acc[mi][ni][r] * SCALE_QK - FIXED_M);
                P[(size_t)row * S_LEN + col] = f2bf(p);
                rs += p;
            }
            rs += __shfl_xor(rs, 1);
            rs += __shfl_xor(rs, 2);
            rs += __shfl_xor(rs, 4);
            rs += __shfl_xor(rs, 8);
            if (ln == 0) lpart[(size_t)row * 64 + blockIdx.y * 4 + wn] = rs;
        }
}

// ---------------- O_p[split] = P[:, ks] @ vt[:, ks]^T (bf16 partials) ----------------
__launch_bounds__(512, 2)
__global__ void gemm_pv2(const unsigned short* __restrict__ P,   // [S][S]
                         const unsigned short* __restrict__ vt,  // [F][S]
                         unsigned short* __restrict__ O_p) {     // [PSPLIT][S][F]
    extern __shared__ unsigned short smem[];
    const int nb = blockIdx.y & 1, split = blockIdx.y >> 1;
    const int m0 = blockIdx.x * 256, n0 = nb * 256;
    f32x4 acc[8][4];
    f32x4 z = {0.f, 0.f, 0.f, 0.f};
#pragma unroll
    for (int i = 0; i < 8; ++i)
#pragma unroll
        for (int j = 0; j < 4; ++j) acc[i][j] = z;

    kloop256(P, S_LEN, vt, S_LEN, m0, n0, split * (S_LEN / PSPLIT), smem, acc);

    unsigned short* Op = O_p + (size_t)split * S_LEN * F_DIM;
    const int tid = threadIdx.x;
    const int w = tid >> 6, l = tid & 63, quad = l >> 4, ln = l & 15;
    const int wm = w >> 2, wn = w & 3;
#pragma unroll
    for (int mi = 0; mi < 8; ++mi)
#pragma unroll
        for (int ni = 0; ni < 4; ++ni)
#pragma unroll
            for (int r = 0; r < 4; ++r) {
                int row = m0 + wm * 128 + mi * 16 + quad * 4 + r;
                int col = n0 + wn * 64 + ni * 16 + ln;
                Op[(size_t)row * F_DIM + col] = f2bf(acc[mi][ni][r]);
            }
}

// ======== legacy 128x128 K-loop (BK=64) — used by fused final gemm ========
#define GEMM_KLOOP(XPTR, LDX, WPTR, LDW, KBEG, KEND)                                  \
    for (int k0 = (KBEG); k0 < (KEND); k0 += 64) {                                    \
        __syncthreads();                                                              \
        _Pragma("unroll")                                                             \
        for (int i = 0; i < 2; ++i) {                                                 \
            int c = w * 2 + i;                                                        \
            _Pragma("unroll")                                                         \
            for (int kh = 0; kh < 2; ++kh) {                                          \
                load_lds16((XPTR) + (size_t)(m0 + c * 16 + ln) * (LDX) + k0 + kh * 32 + quad * 8, \
                           &As[(c * 2 + kh) * 512]);                                  \
                load_lds16((WPTR) + (size_t)(n0 + c * 16 + ln) * (LDW) + k0 + kh * 32 + quad * 8, \
                           &Bs[(c * 2 + kh) * 512]);                                  \
            }                                                                         \
        }                                                                             \
        __syncthreads();                                                              \
        _Pragma("unroll")                                                             \
        for (int kh = 0; kh < 2; ++kh) {                                              \
            bf16x8 af2[4], bfr2[4];                                                   \
            _Pragma("unroll")                                                         \
            for (int mt = 0; mt < 4; ++mt)                                            \
                af2[mt] = *(const bf16x8*)&As[((wr * 4 + mt) * 2 + kh) * 512 + l * 8]; \
            _Pragma("unroll")                                                         \
            for (int nt = 0; nt < 4; ++nt)                                            \
                bfr2[nt] = *(const bf16x8*)&Bs[((wc * 4 + nt) * 2 + kh) * 512 + l * 8]; \
            _Pragma("unroll")                                                         \
            for (int mt = 0; mt < 4; ++mt)                                            \
                _Pragma("unroll")                                                     \
                for (int nt = 0; nt < 4; ++nt)                                        \
                    acc[mt][nt] = __builtin_amdgcn_mfma_f32_16x16x32_bf16(            \
                        af2[mt], bfr2[nt], acc[mt][nt], 0, 0, 0);                     \
        }                                                                             \
    }

// ---------------- final projection, fused: out = relu(res @ Wo^T + bo), f32 ----------------
__launch_bounds__(256, 2)
__global__ void gemm_final(const unsigned short* __restrict__ X,   // res [S][F]
                           const unsigned short* __restrict__ W,   // Wo [F][F]
                           const float* __restrict__ bias,
                           float* __restrict__ out) {
    __shared__ __align__(16) unsigned short As[16 * 512];
    __shared__ __align__(16) unsigned short Bs[16 * 512];
    const int n0 = blockIdx.y * 128;
    const int m0 = blockIdx.x * 128;
    const int tid = threadIdx.x;
    const int w = tid >> 6, l = tid & 63, quad = l >> 4, ln = l & 15;
    const int wr = w >> 1, wc = w & 1;

    f32x4 acc[4][4];
    f32x4 zero4 = {0.f, 0.f, 0.f, 0.f};
#pragma unroll
    for (int i = 0; i < 4; ++i)
#pragma unroll
        for (int j = 0; j < 4; ++j) acc[i][j] = zero4;

    GEMM_KLOOP(X, F_DIM, W, F_DIM, 0, F_DIM)

#pragma unroll
    for (int mt = 0; mt < 4; ++mt)
#pragma unroll
        for (int nt = 0; nt < 4; ++nt)
#pragma unroll
            for (int r = 0; r < 4; ++r) {
                int row = m0 + wr * 64 + mt * 16 + quad * 4 + r;
                int col = n0 + wc * 64 + nt * 16 + ln;
                out[(size_t)row * F_DIM + col] =
                    fmaxf(acc[mt][nt][r] + bias[col], 0.f);
            }
}

// ---------------- combine: denom + q_att dot + split-sum + elementwise fusion ----------------
__global__ void combine_kernel(const unsigned short* __restrict__ O_p,
                               const float* __restrict__ lpart,   // [S][64]
                               const unsigned short* __restrict__ qq,
                               const unsigned short* __restrict__ qk,
                               const unsigned short* __restrict__ qv,
                               unsigned short* __restrict__ res_bf) {
    int row = blockIdx.x;
    int t = threadIdx.x;  // 128 threads = 2 waves
    int wv = t >> 6, l = t & 63;
    __shared__ float ws[4];

    ushort4 a = *(const ushort4*)(qq + (size_t)row * F_DIM + t * 4);
    ushort4 b = *(const ushort4*)(qk + (size_t)row * F_DIM + t * 4);
    float dotp = bf2f(a.x) * bf2f(b.x) + bf2f(a.y) * bf2f(b.y) +
                 bf2f(a.z) * bf2f(b.z) + bf2f(a.w) * bf2f(b.w);
    float lp = (t < 64) ? lpart[(size_t)row * 64 + t] : 0.f;
#pragma unroll
    for (int off = 32; off >= 1; off >>= 1) {
        dotp += __shfl_xor(dotp, off);
        lp += __shfl_xor(lp, off);
    }
    if (l == 0) { ws[wv] = dotp; ws[2 + wv] = lp; }
    __syncthreads();
    float qa = ws[0] + ws[1];
    float denom = __expf(qa * SCALE_QK - FIXED_M) + ws[2] + ws[3];
    float inv = 1.f / denom;

    // thread t handles f in [t*4, t*4+4)
    float4 s = {0.f, 0.f, 0.f, 0.f};
#pragma unroll
    for (int i = 0; i < PSPLIT; ++i) {
        ushort4 o = *(const ushort4*)(O_p + ((size_t)i * S_LEN + row) * F_DIM + t * 4);
        s.x += bf2f(o.x); s.y += bf2f(o.y); s.z += bf2f(o.z); s.w += bf2f(o.w);
    }
    ushort4 qvv = *(const ushort4*)(qv + (size_t)row * F_DIM + t * 4);
    ushort4 o;
    o.x = f2bf(bf2f(qvv.x) * qa + s.x * inv);
    o.y = f2bf(bf2f(qvv.y) * qa + s.y * inv);
    o.z = f2bf(bf2f(qvv.z) * qa + s.z * inv);
    o.w = f2bf(bf2f(qvv.w) * qa + s.w * inv);
    *(ushort4*)(res_bf + (size_t)row * F_DIM + t * 4) = o;
}

extern "C" void kernel_launch(void* const* d_in, const int* in_sizes, int n_in,
                              void* d_out, int out_size, void* d_ws, size_t ws_size,
                              hipStream_t stream) {
    const float* q  = (const float*)d_in[0];
    const float* k  = (const float*)d_in[1];
    const float* v  = (const float*)d_in[2];
    const float* Wq = (const float*)d_in[3];
    const float* bq = (const float*)d_in[4];
    const float* Wk = (const float*)d_in[5];
    const float* bk = (const float*)d_in[6];
    const float* Wv = (const float*)d_in[7];
    const float* bv = (const float*)d_in[8];
    const float* Wo = (const float*)d_in[9];
    const float* bo = (const float*)d_in[10];
    float* out = (float*)d_out;

    char* p = (char*)d_ws;
    auto alloc = [&](size_t bytes) -> char* {
        char* r = p; p += (bytes + 255) & ~(size_t)255; return r;
    };
    const size_t SF = (size_t)S_LEN * F_DIM;
    unsigned short* q_bf  = (unsigned short*)alloc(SF * 2);
    unsigned short* k_bf  = (unsigned short*)alloc(SF * 2);
    unsigned short* v_bf  = (unsigned short*)alloc(SF * 2);
    unsigned short* qq_bf = (unsigned short*)alloc(SF * 2);
    unsigned short* kk_bf = (unsigned short*)alloc(SF * 2);
    unsigned short* vv_bf = (unsigned short*)alloc(SF * 2);
    unsigned short* vt_bf = (unsigned short*)alloc(SF * 2);
    unsigned short* qk_bf = (unsigned short*)alloc(SF * 2);
    unsigned short* qv_bf = (unsigned short*)alloc(SF * 2);
    unsigned short* res_bf = (unsigned short*)alloc(SF * 2);
    unsigned short* wq_bf = (unsigned short*)alloc((size_t)F_DIM * F_DIM * 2);
    unsigned short* wk_bf = (unsigned short*)alloc((size_t)F_DIM * F_DIM * 2);
    unsigned short* wv_bf = (unsigned short*)alloc((size_t)F_DIM * F_DIM * 2);
    unsigned short* wo_bf = (unsigned short*)alloc((size_t)F_DIM * F_DIM * 2);
    unsigned short* P_bf  = (unsigned short*)alloc((size_t)S_LEN * S_LEN * 2);  // 33.5 MB
    float* lpart = (float*)alloc((size_t)S_LEN * 64 * 4);                        // [S][64]
    unsigned short* O_p = (unsigned short*)alloc((size_t)PSPLIT * SF * 2);      // 32 MB

    static int attr_done = 0;
    if (!attr_done) {
        hipFuncSetAttribute((const void*)gemm_proj2,
                            hipFuncAttributeMaxDynamicSharedMemorySize, 131072);
        hipFuncSetAttribute((const void*)gemm_exp2,
                            hipFuncAttributeMaxDynamicSharedMemorySize, 131072);
        hipFuncSetAttribute((const void*)gemm_pv2,
                            hipFuncAttributeMaxDynamicSharedMemorySize, 131072);
        attr_done = 1;
    }

    CastArgs ca;
    ca.src[0] = q;  ca.dst[0] = q_bf;  ca.n4[0] = (int)(SF / 4);
    ca.src[1] = k;  ca.dst[1] = k_bf;  ca.n4[1] = (int)(SF / 4);
    ca.src[2] = v;  ca.dst[2] = v_bf;  ca.n4[2] = (int)(SF / 4);
    ca.src[3] = Wq; ca.dst[3] = wq_bf; ca.n4[3] = F_DIM * F_DIM / 4;
    ca.src[4] = Wk; ca.dst[4] = wk_bf; ca.n4[4] = F_DIM * F_DIM / 4;
    ca.src[5] = Wv; ca.dst[5] = wv_bf; ca.n4[5] = F_DIM * F_DIM / 4;
    ca.src[6] = Wo; ca.dst[6] = wo_bf; ca.n4[6] = F_DIM * F_DIM / 4;
    cast_all<<<dim3((unsigned)(SF / 4 / 256), 7), 256, 0, stream>>>(ca);

    GemmArgs ga;
    ga.d[0] = { q_bf, wq_bf, bq, qq_bf, nullptr, 1 };
    ga.d[1] = { k_bf, wk_bf, bk, kk_bf, nullptr, 1 };
    ga.d[2] = { v_bf, wv_bf, bv, vv_bf, nullptr, 1 };
    ga.d[3] = { q_bf, wk_bf, bk, qk_bf, nullptr, 0 };
    ga.d[4] = { q_bf, wv_bf, bv, qv_bf, nullptr, 0 };
    gemm_proj2<<<dim3(S_LEN / 256, 10), 512, 131072, stream>>>(ga);

    transpose_bf16<<<dim3(S_LEN / 64, F_DIM / 64), 256, 0, stream>>>(vv_bf, vt_bf);

    gemm_exp2<<<dim3(S_LEN / 256, S_LEN / 256), 512, 131072, stream>>>(qq_bf, kk_bf, P_bf, lpart);

    gemm_pv2<<<dim3(S_LEN / 256, 2 * PSPLIT), 512, 131072, stream>>>(P_bf, vt_bf, O_p);

    combine_kernel<<<S_LEN, 128, 0, stream>>>(O_p, lpart, qq_bf, qk_bf, qv_bf, res_bf);

    gemm_final<<<dim3(S_LEN / 128, 4), 256, 0, stream>>>(res_bf, wo_bf, bo, out);
}